// Round 1
// baseline (643.079 us; speedup 1.0000x reference)
//
#include <hip/hip_runtime.h>
#include <math.h>

#define L_SEQ   2048
#define DLLM    768
#define E_DIM   64
#define NSLICE  16
#define SCALE   0.125f   // 1/sqrt(64)
#define EPSV    1e-5f

__device__ __forceinline__ float dot4(const float4& a, const float4& b) {
    return a.x * b.x + a.y * b.y + a.z * b.z + a.w * b.w;
}
__device__ __forceinline__ void fma4(float4& o, float a, const float4& b) {
    o.x += a * b.x; o.y += a * b.y; o.z += a * b.z; o.w += a * b.w;
}
__device__ __forceinline__ void scale4(float4& o, float s) {
    o.x *= s; o.y *= s; o.z *= s; o.w *= s;
}

// ---------------------------------------------------------------------------
// Projection: [32768 x 768] @ [768 x 192] + bias -> q,k,v each [32768 x 64]
// block: 256 threads, tile 64 rows x 192 cols, k-step 48
// ---------------------------------------------------------------------------
#define PJ_BK 48
#define PJ_AP 52   // padded A leading dim (floats)

__global__ __launch_bounds__(256)
void proj_kernel(const float* __restrict__ info,
                 const float* __restrict__ Wq, const float* __restrict__ bq,
                 const float* __restrict__ Wk, const float* __restrict__ bk,
                 const float* __restrict__ Wv, const float* __restrict__ bv,
                 float* __restrict__ qo, float* __restrict__ ko, float* __restrict__ vo)
{
    __shared__ float As[64 * PJ_AP];    // 13312 B
    __shared__ float Bs[PJ_BK * 192];   // 36864 B

    const int tid = threadIdx.x;
    const int tx  = tid & 15;
    const int ty  = tid >> 4;
    const int r0  = blockIdx.x * 64;

    const float* Wsel[3] = {Wq, Wk, Wv};
    const float* bsel[3] = {bq, bk, bv};

    float4 acc[4][3];
    #pragma unroll
    for (int i = 0; i < 4; ++i)
        #pragma unroll
        for (int u = 0; u < 3; ++u) acc[i][u] = make_float4(0.f, 0.f, 0.f, 0.f);

    for (int ks = 0; ks < DLLM; ks += PJ_BK) {
        __syncthreads();
        // stage A: 64 rows x 48 floats = 768 float4 (3 per thread)
        #pragma unroll
        for (int u = 0; u < 3; ++u) {
            int f   = u * 256 + tid;
            int row = f / 12, c4 = f % 12;
            float4 val = *reinterpret_cast<const float4*>(
                info + (size_t)(r0 + row) * DLLM + ks + c4 * 4);
            *reinterpret_cast<float4*>(&As[row * PJ_AP + c4 * 4]) = val;
        }
        // stage B: 48 rows x 192 floats = 2304 float4 (9 per thread)
        #pragma unroll
        for (int u = 0; u < 9; ++u) {
            int f   = u * 256 + tid;
            int kk  = f / 48, c4 = f % 48;
            int sel = c4 >> 4, c16 = c4 & 15;
            float4 val = *reinterpret_cast<const float4*>(
                Wsel[sel] + (size_t)(ks + kk) * E_DIM + c16 * 4);
            *reinterpret_cast<float4*>(&Bs[kk * 192 + c4 * 4]) = val;
        }
        __syncthreads();

        #pragma unroll
        for (int kq = 0; kq < 12; ++kq) {
            float4 a4[4];
            #pragma unroll
            for (int i = 0; i < 4; ++i)
                a4[i] = *reinterpret_cast<const float4*>(&As[(4 * ty + i) * PJ_AP + 4 * kq]);
            #pragma unroll
            for (int k2 = 0; k2 < 4; ++k2) {
                float4 b4[3];
                #pragma unroll
                for (int u = 0; u < 3; ++u)
                    b4[u] = *reinterpret_cast<const float4*>(&Bs[(4 * kq + k2) * 192 + 12 * tx + 4 * u]);
                #pragma unroll
                for (int i = 0; i < 4; ++i) {
                    float a = (k2 == 0) ? a4[i].x : (k2 == 1) ? a4[i].y
                            : (k2 == 2) ? a4[i].z : a4[i].w;
                    #pragma unroll
                    for (int u = 0; u < 3; ++u) fma4(acc[i][u], a, b4[u]);
                }
            }
        }
    }

    // epilogue: + bias, scatter to q/k/v
    #pragma unroll
    for (int i = 0; i < 4; ++i) {
        const int r = r0 + 4 * ty + i;
        #pragma unroll
        for (int u = 0; u < 3; ++u) {
            int col = 12 * tx + 4 * u;
            int sel = col >> 6;
            int cc  = col & 63;
            float4 b4 = *reinterpret_cast<const float4*>(bsel[sel] + cc);
            float4 o  = acc[i][u];
            o.x += b4.x; o.y += b4.y; o.z += b4.z; o.w += b4.w;
            float* dst = (sel == 0) ? qo : (sel == 1) ? ko : vo;
            *reinterpret_cast<float4*>(dst + (size_t)r * E_DIM + cc) = o;
        }
    }
}

// ---------------------------------------------------------------------------
// Attention: per (slice, 64-row tile), flash-style online softmax over 32
// chunks of 64 keys. p reuses the K LDS buffer.
// thread map: tx = tid&15, ty = tid>>4; q-rows 4*ty+i; scores m = tx+16*j;
// output e-cols = 4*tx.
// ---------------------------------------------------------------------------
#define PADR 68

__global__ __launch_bounds__(256)
void attn_kernel(const float* __restrict__ qg, const float* __restrict__ kg,
                 const float* __restrict__ vg, float* __restrict__ att)
{
    __shared__ float qs[64 * PADR];
    __shared__ float kx[64 * PADR];   // K chunk, then reused for P
    __shared__ float vs[64 * PADR];

    const int tid = threadIdx.x;
    const int tx  = tid & 15;
    const int ty  = tid >> 4;
    const int slice = blockIdx.y;
    const int r0    = blockIdx.x * 64;
    const size_t sbase = (size_t)slice * L_SEQ * E_DIM;

    // stage Q tile (once)
    #pragma unroll
    for (int u = 0; u < 4; ++u) {
        int f = u * 256 + tid;
        int row = f >> 4, e4 = f & 15;
        float4 val = *reinterpret_cast<const float4*>(
            qg + sbase + (size_t)(r0 + row) * E_DIM + e4 * 4);
        *reinterpret_cast<float4*>(&qs[row * PADR + e4 * 4]) = val;
    }

    float4 o4[4];
    float  M[4], l[4];
    #pragma unroll
    for (int i = 0; i < 4; ++i) {
        o4[i] = make_float4(0.f, 0.f, 0.f, 0.f);
        M[i] = -1e30f; l[i] = 0.f;
    }

    for (int ch = 0; ch < L_SEQ / 64; ++ch) {
        const int m0 = ch * 64;
        __syncthreads();   // B1: previous PV finished reading kx(=P), vs
        #pragma unroll
        for (int u = 0; u < 4; ++u) {
            int f = u * 256 + tid;
            int row = f >> 4, e4 = f & 15;
            float4 kv = *reinterpret_cast<const float4*>(
                kg + sbase + (size_t)(m0 + row) * E_DIM + e4 * 4);
            *reinterpret_cast<float4*>(&kx[row * PADR + e4 * 4]) = kv;
            float4 vv = *reinterpret_cast<const float4*>(
                vg + sbase + (size_t)(m0 + row) * E_DIM + e4 * 4);
            *reinterpret_cast<float4*>(&vs[row * PADR + e4 * 4]) = vv;
        }
        __syncthreads();   // B2: K,V staged

        // scores: s[i][j] = q[4ty+i] . k[tx+16j]
        float s[4][4];
        #pragma unroll
        for (int i = 0; i < 4; ++i)
            #pragma unroll
            for (int j = 0; j < 4; ++j) s[i][j] = 0.f;

        #pragma unroll
        for (int eq = 0; eq < 16; ++eq) {
            float4 qv[4], kv[4];
            #pragma unroll
            for (int i = 0; i < 4; ++i)
                qv[i] = *reinterpret_cast<const float4*>(&qs[(4 * ty + i) * PADR + 4 * eq]);
            #pragma unroll
            for (int j = 0; j < 4; ++j)
                kv[j] = *reinterpret_cast<const float4*>(&kx[(tx + 16 * j) * PADR + 4 * eq]);
            #pragma unroll
            for (int i = 0; i < 4; ++i)
                #pragma unroll
                for (int j = 0; j < 4; ++j)
                    s[i][j] += dot4(qv[i], kv[j]);
        }
        __syncthreads();   // B3: all waves done reading kx as K

        // online softmax; write p into kx
        #pragma unroll
        for (int i = 0; i < 4; ++i) {
            float t0 = s[i][0] * SCALE, t1 = s[i][1] * SCALE;
            float t2 = s[i][2] * SCALE, t3 = s[i][3] * SCALE;
            float mx = fmaxf(fmaxf(t0, t1), fmaxf(t2, t3));
            mx = fmaxf(mx, __shfl_xor(mx, 1));
            mx = fmaxf(mx, __shfl_xor(mx, 2));
            mx = fmaxf(mx, __shfl_xor(mx, 4));
            mx = fmaxf(mx, __shfl_xor(mx, 8));
            float Mn = fmaxf(M[i], mx);
            float f  = __expf(M[i] - Mn);
            float p0 = __expf(t0 - Mn), p1 = __expf(t1 - Mn);
            float p2 = __expf(t2 - Mn), p3 = __expf(t3 - Mn);
            kx[(4 * ty + i) * PADR + tx +  0] = p0;
            kx[(4 * ty + i) * PADR + tx + 16] = p1;
            kx[(4 * ty + i) * PADR + tx + 32] = p2;
            kx[(4 * ty + i) * PADR + tx + 48] = p3;
            l[i] = l[i] * f + (p0 + p1 + p2 + p3);
            scale4(o4[i], f);
            M[i] = Mn;
        }
        __syncthreads();   // B4: P visible

        // PV: o[i][e] += sum_m p[row][m] * v[m][e]
        #pragma unroll
        for (int jq = 0; jq < 16; ++jq) {
            float4 p4[4];
            #pragma unroll
            for (int i = 0; i < 4; ++i)
                p4[i] = *reinterpret_cast<const float4*>(&kx[(4 * ty + i) * PADR + 4 * jq]);
            #pragma unroll
            for (int jj = 0; jj < 4; ++jj) {
                float4 vv = *reinterpret_cast<const float4*>(&vs[(4 * jq + jj) * PADR + 4 * tx]);
                #pragma unroll
                for (int i = 0; i < 4; ++i) {
                    float p = (jj == 0) ? p4[i].x : (jj == 1) ? p4[i].y
                            : (jj == 2) ? p4[i].z : p4[i].w;
                    fma4(o4[i], p, vv);
                }
            }
        }
    }

    // finalize: reduce l across the 16-lane tx group, divide, store
    #pragma unroll
    for (int i = 0; i < 4; ++i) {
        float li = l[i];
        li += __shfl_xor(li, 1);
        li += __shfl_xor(li, 2);
        li += __shfl_xor(li, 4);
        li += __shfl_xor(li, 8);
        float inv = 1.f / li;
        scale4(o4[i], inv);
        *reinterpret_cast<float4*>(
            att + sbase + (size_t)(r0 + 4 * ty + i) * E_DIM + 4 * tx) = o4[i];
    }
}

// ---------------------------------------------------------------------------
// InstanceNorm over each (slice) of [L_SEQ x E_DIM]
// ---------------------------------------------------------------------------
__global__ __launch_bounds__(256)
void norm_stats(const float* __restrict__ att, float* __restrict__ stats)
{
    const int slice = blockIdx.x;
    const int tid = threadIdx.x;
    const size_t base = (size_t)slice * L_SEQ * E_DIM;
    float s = 0.f, sq = 0.f;
    for (int it = 0; it < 128; ++it) {
        float4 v = *reinterpret_cast<const float4*>(att + base + (size_t)(it * 256 + tid) * 4);
        s  += v.x + v.y + v.z + v.w;
        sq += v.x * v.x + v.y * v.y + v.z * v.z + v.w * v.w;
    }
    for (int mask = 1; mask < 64; mask <<= 1) {
        s  += __shfl_xor(s,  mask);
        sq += __shfl_xor(sq, mask);
    }
    __shared__ float red[8];
    const int wid = tid >> 6;
    if ((tid & 63) == 0) { red[wid * 2] = s; red[wid * 2 + 1] = sq; }
    __syncthreads();
    if (tid == 0) {
        float S  = red[0] + red[2] + red[4] + red[6];
        float SQ = red[1] + red[3] + red[5] + red[7];
        const float N = (float)(L_SEQ * E_DIM);
        float mean = S / N;
        float var  = SQ / N - mean * mean;
        stats[slice * 2]     = mean;
        stats[slice * 2 + 1] = rsqrtf(var + EPSV);
    }
}

__global__ __launch_bounds__(256)
void norm_apply(const float* __restrict__ att, const float* __restrict__ stats,
                float* __restrict__ out)
{
    const int i4 = blockIdx.x * 256 + threadIdx.x;
    const size_t fl = (size_t)i4 * 4;
    const int slice = (int)(fl >> 17);   // / (2048*64)
    const float mean = stats[slice * 2];
    const float inv  = stats[slice * 2 + 1];
    float4 v = *reinterpret_cast<const float4*>(att + fl);
    float4 o;
    o.x = (v.x - mean) * inv;
    o.y = (v.y - mean) * inv;
    o.z = (v.z - mean) * inv;
    o.w = (v.w - mean) * inv;
    *reinterpret_cast<float4*>(out + fl) = o;
}

// ---------------------------------------------------------------------------
extern "C" void kernel_launch(void* const* d_in, const int* in_sizes, int n_in,
                              void* d_out, int out_size, void* d_ws, size_t ws_size,
                              hipStream_t stream)
{
    const float* info = (const float*)d_in[0];
    const float* Wq   = (const float*)d_in[1];
    const float* bq   = (const float*)d_in[2];
    const float* Wk   = (const float*)d_in[3];
    const float* bk   = (const float*)d_in[4];
    const float* Wv   = (const float*)d_in[5];
    const float* bv   = (const float*)d_in[6];

    float* ws = (float*)d_ws;
    const size_t SLICE_N = (size_t)NSLICE * L_SEQ * E_DIM;  // 2,097,152
    float* q     = ws;
    float* k     = ws + SLICE_N;
    float* v     = ws + 2 * SLICE_N;
    float* att   = ws + 3 * SLICE_N;
    float* stats = ws + 4 * SLICE_N;
    float* out   = (float*)d_out;

    proj_kernel<<<512, 256, 0, stream>>>(info, Wq, bq, Wk, bk, Wv, bv, q, k, v);
    attn_kernel<<<dim3(L_SEQ / 64, NSLICE), 256, 0, stream>>>(q, k, v, att);
    norm_stats<<<NSLICE, 256, 0, stream>>>(att, stats);
    norm_apply<<<2048, 256, 0, stream>>>(att, stats, out);
}

// Round 3
// 270.843 us; speedup vs baseline: 2.3744x; 2.3744x over previous
//
#include <hip/hip_runtime.h>
#include <math.h>

#define L_SEQ   2048
#define DLLM    768
#define E_DIM   64
#define NSLICE  16
#define EPSV    1e-5f

typedef _Float16 f16;
typedef _Float16 f16x8 __attribute__((ext_vector_type(8)));
typedef _Float16 f16x4 __attribute__((ext_vector_type(4)));
typedef float    f32x4 __attribute__((ext_vector_type(4)));

// ---------------------------------------------------------------------------
// prep: Wt16[192][768] = [Wq^T * 0.125 | Wk^T | Wv^T] fp16 ; bias[192] fp32
// ---------------------------------------------------------------------------
__global__ __launch_bounds__(256)
void prep_kernel(const float* __restrict__ Wq, const float* __restrict__ bq,
                 const float* __restrict__ Wk, const float* __restrict__ bk,
                 const float* __restrict__ Wv, const float* __restrict__ bv,
                 f16* __restrict__ Wt, float* __restrict__ bias)
{
    int b = blockIdx.x;
    if (b < 192) {
        int sel = b >> 6, c = b & 63;
        const float* W = (sel == 0) ? Wq : (sel == 1) ? Wk : Wv;
        float s = (sel == 0) ? 0.125f : 1.0f;
        for (int kd = threadIdx.x; kd < DLLM; kd += 256)
            Wt[b * DLLM + kd] = (f16)(W[kd * 64 + c] * s);
    } else {
        int t = threadIdx.x;
        if (t < 192) {
            int sel = t >> 6, c = t & 63;
            const float* bb = (sel == 0) ? bq : (sel == 1) ? bk : bv;
            bias[t] = bb[c] * ((sel == 0) ? 0.125f : 1.0f);
        }
    }
}

// ---------------------------------------------------------------------------
// proj: [32768 x 768] fp32 @ Wt^T -> q,k,v fp16 [32768 x 64] (q pre-scaled)
// tile 128x192, BK=64, 4 waves (2x2), wave tile 64x96 (4m x 6n frags)
// ---------------------------------------------------------------------------
#define PSTR 72   // fp16 stride: 144 B rows, 16B-aligned

__global__ __launch_bounds__(256)
void proj_mfma(const float* __restrict__ info, const f16* __restrict__ Wt,
               const float* __restrict__ bias,
               f16* __restrict__ q16, f16* __restrict__ k16, f16* __restrict__ v16)
{
    __shared__ f16 As[128 * PSTR];   // 18432 B
    __shared__ f16 Bs[192 * PSTR];   // 27648 B

    const int tid = threadIdx.x;
    const int l   = tid & 63;
    const int wid = tid >> 6;
    const int l15 = l & 15, lg = l >> 4;
    const int wm  = (wid >> 1) * 64;   // wave m base in tile
    const int wn  = (wid & 1) * 96;    // wave n base in tile
    const int r0  = blockIdx.x * 128;

    f32x4 acc[4][6];
    #pragma unroll
    for (int i = 0; i < 4; ++i)
        #pragma unroll
        for (int j = 0; j < 6; ++j) acc[i][j] = (f32x4)(0.0f);

    for (int k0 = 0; k0 < DLLM; k0 += 64) {
        __syncthreads();
        // stage A: 128 rows x 64 fp32 -> fp16
        #pragma unroll
        for (int u = 0; u < 8; ++u) {
            int f = u * 256 + tid;
            int row = f >> 4, c4 = f & 15;
            float4 v = *reinterpret_cast<const float4*>(
                info + (size_t)(r0 + row) * DLLM + k0 + c4 * 4);
            f16x4 h;
            h[0] = (f16)v.x; h[1] = (f16)v.y; h[2] = (f16)v.z; h[3] = (f16)v.w;
            *reinterpret_cast<f16x4*>(&As[row * PSTR + c4 * 4]) = h;
        }
        // stage B: Wt rows 192 x 64 fp16
        #pragma unroll
        for (int u = 0; u < 6; ++u) {
            int f = u * 256 + tid;
            int row = f >> 3, c8 = f & 7;
            f16x8 v = *reinterpret_cast<const f16x8*>(Wt + (size_t)row * DLLM + k0 + c8 * 8);
            *reinterpret_cast<f16x8*>(&Bs[row * PSTR + c8 * 8]) = v;
        }
        __syncthreads();

        #pragma unroll
        for (int kf = 0; kf < 2; ++kf) {
            f16x8 af[4], bf[6];
            #pragma unroll
            for (int mi = 0; mi < 4; ++mi)
                af[mi] = *reinterpret_cast<const f16x8*>(
                    &As[(wm + mi * 16 + l15) * PSTR + kf * 32 + lg * 8]);
            #pragma unroll
            for (int ni = 0; ni < 6; ++ni)
                bf[ni] = *reinterpret_cast<const f16x8*>(
                    &Bs[(wn + ni * 16 + l15) * PSTR + kf * 32 + lg * 8]);
            #pragma unroll
            for (int mi = 0; mi < 4; ++mi)
                #pragma unroll
                for (int ni = 0; ni < 6; ++ni)
                    acc[mi][ni] = __builtin_amdgcn_mfma_f32_16x16x32_f16(
                        af[mi], bf[ni], acc[mi][ni], 0, 0, 0);
        }
    }

    // epilogue: + bias, scatter
    #pragma unroll
    for (int ni = 0; ni < 6; ++ni) {
        int n = wn + ni * 16 + l15;
        float bcol = bias[n];
        int sel = n >> 6, cc = n & 63;
        f16* dst = (sel == 0) ? q16 : (sel == 1) ? k16 : v16;
        #pragma unroll
        for (int mi = 0; mi < 4; ++mi)
            #pragma unroll
            for (int rr = 0; rr < 4; ++rr) {
                int row = r0 + wm + mi * 16 + lg * 4 + rr;
                dst[(size_t)row * E_DIM + cc] = (f16)(acc[mi][ni][rr] + bcol);
            }
    }
}

// ---------------------------------------------------------------------------
// attn: flash attention, QBLK=64 (4 waves x 16 rows), KVBLK=64.
// Q/K fragments straight from global (L2-resident). V transposed per-chunk
// into a bank-swizzled LDS tile. P via wave-private LDS slab (no barrier).
// ---------------------------------------------------------------------------
#define VSTR 72

__global__ __launch_bounds__(256)
void attn_mfma(const f16* __restrict__ q16, const f16* __restrict__ k16,
               const f16* __restrict__ v16, float* __restrict__ att)
{
    __shared__ f16 Vt[64 * VSTR];        // 9216 B: V^T chunk, kv-col swizzled
    __shared__ f16 Pl[4 * 16 * VSTR];    // 9216 B: wave-private P slabs

    const int tid = threadIdx.x;
    const int l   = tid & 63;
    const int wid = tid >> 6;
    const int l15 = l & 15, lg = l >> 4;
    const int slice = blockIdx.y;
    const int m0 = blockIdx.x * 64 + wid * 16;
    const f16* qp = q16 + (size_t)slice * L_SEQ * E_DIM;
    const f16* kp = k16 + (size_t)slice * L_SEQ * E_DIM;
    const f16* vp = v16 + (size_t)slice * L_SEQ * E_DIM;
    f16* P = &Pl[wid * 16 * VSTR];

    // Q fragments (registers for the whole kernel); q pre-scaled by 1/8
    f16x8 qf[2];
    #pragma unroll
    for (int kf = 0; kf < 2; ++kf)
        qf[kf] = *reinterpret_cast<const f16x8*>(
            qp + (size_t)(m0 + l15) * E_DIM + kf * 32 + lg * 8);

    f32x4 oacc[4];
    #pragma unroll
    for (int ni = 0; ni < 4; ++ni) oacc[ni] = (f32x4)(0.0f);
    float M[4] = {-1e30f, -1e30f, -1e30f, -1e30f};
    float Lr[4] = {0.f, 0.f, 0.f, 0.f};

    for (int kv0 = 0; kv0 < L_SEQ; kv0 += 64) {
        __syncthreads();   // previous PV done reading Vt

        // stage V chunk transposed into Vt with XOR swizzle:
        // element V[kv0+r][e] stored at Vt[e*VSTR + (r ^ ((e>>3)<<3))]
        #pragma unroll
        for (int u = 0; u < 2; ++u) {
            int f  = u * 256 + tid;
            int r  = f >> 3;      // kv row 0..63
            int c8 = f & 7;       // e-group (e = c8*8 + j)
            f16x8 h = *reinterpret_cast<const f16x8*>(
                vp + (size_t)(kv0 + r) * E_DIM + c8 * 8);
            int col = r ^ (c8 << 3);
            #pragma unroll
            for (int j = 0; j < 8; ++j)
                Vt[(c8 * 8 + j) * VSTR + col] = h[j];
        }

        // S = Q K^T (K from global; overlaps Vt staging latency)
        f32x4 s[4];
        #pragma unroll
        for (int ni = 0; ni < 4; ++ni) s[ni] = (f32x4)(0.0f);
        #pragma unroll
        for (int kf = 0; kf < 2; ++kf)
            #pragma unroll
            for (int ni = 0; ni < 4; ++ni) {
                f16x8 kb = *reinterpret_cast<const f16x8*>(
                    kp + (size_t)(kv0 + ni * 16 + l15) * E_DIM + kf * 32 + lg * 8);
                s[ni] = __builtin_amdgcn_mfma_f32_16x16x32_f16(qf[kf], kb, s[ni], 0, 0, 0);
            }

        // online softmax; P -> wave-private LDS
        #pragma unroll
        for (int r = 0; r < 4; ++r) {
            float v0 = s[0][r], v1 = s[1][r], v2 = s[2][r], v3 = s[3][r];
            float mx = fmaxf(fmaxf(v0, v1), fmaxf(v2, v3));
            mx = fmaxf(mx, __shfl_xor(mx, 1));
            mx = fmaxf(mx, __shfl_xor(mx, 2));
            mx = fmaxf(mx, __shfl_xor(mx, 4));
            mx = fmaxf(mx, __shfl_xor(mx, 8));
            float mn  = fmaxf(M[r], mx);
            float fsc = __expf(M[r] - mn);
            M[r] = mn;
            float p0 = __expf(v0 - mn), p1 = __expf(v1 - mn);
            float p2 = __expf(v2 - mn), p3 = __expf(v3 - mn);
            int prow = (lg * 4 + r) * VSTR + l15;
            P[prow +  0] = (f16)p0;
            P[prow + 16] = (f16)p1;
            P[prow + 32] = (f16)p2;
            P[prow + 48] = (f16)p3;
            Lr[r] = Lr[r] * fsc + (p0 + p1 + p2 + p3);
            oacc[0][r] *= fsc; oacc[1][r] *= fsc;
            oacc[2][r] *= fsc; oacc[3][r] *= fsc;
        }

        __syncthreads();   // Vt staged by all threads

        // PV: O += P * V  (B-frags from swizzled Vt)
        #pragma unroll
        for (int kf = 0; kf < 2; ++kf) {
            f16x8 pa = *reinterpret_cast<const f16x8*>(
                &P[l15 * VSTR + kf * 32 + lg * 8]);
            #pragma unroll
            for (int ni = 0; ni < 4; ++ni) {
                int e   = ni * 16 + l15;
                int col = (kf * 32 + lg * 8) ^ ((e >> 3) << 3);
                f16x8 vb = *reinterpret_cast<const f16x8*>(&Vt[e * VSTR + col]);
                oacc[ni] = __builtin_amdgcn_mfma_f32_16x16x32_f16(pa, vb, oacc[ni], 0, 0, 0);
            }
        }
    }

    // finalize: reduce l across the 16-lane group, divide, store fp32
    #pragma unroll
    for (int r = 0; r < 4; ++r) {
        float lt = Lr[r];
        lt += __shfl_xor(lt, 1);
        lt += __shfl_xor(lt, 2);
        lt += __shfl_xor(lt, 4);
        lt += __shfl_xor(lt, 8);
        float inv = 1.f / lt;
        size_t row = (size_t)slice * L_SEQ + m0 + lg * 4 + r;
        #pragma unroll
        for (int ni = 0; ni < 4; ++ni)
            att[row * E_DIM + ni * 16 + l15] = oacc[ni][r] * inv;
    }
}

// ---------------------------------------------------------------------------
// InstanceNorm: per-block partial sums (no atomics, no init), then apply
// ---------------------------------------------------------------------------
__global__ __launch_bounds__(256)
void stats_kernel(const float* __restrict__ att, float* __restrict__ parts)
{
    const int slice = blockIdx.x >> 4;
    const int part  = blockIdx.x & 15;
    const int tid = threadIdx.x;
    const size_t base = (size_t)slice * L_SEQ * E_DIM + (size_t)part * 8192;
    float s = 0.f, sq = 0.f;
    #pragma unroll
    for (int it = 0; it < 8; ++it) {
        float4 v = *reinterpret_cast<const float4*>(att + base + (size_t)(it * 256 + tid) * 4);
        s  += v.x + v.y + v.z + v.w;
        sq += v.x * v.x + v.y * v.y + v.z * v.z + v.w * v.w;
    }
    for (int m = 1; m < 64; m <<= 1) {
        s  += __shfl_xor(s,  m);
        sq += __shfl_xor(sq, m);
    }
    __shared__ float red[8];
    const int wid = tid >> 6;
    if ((tid & 63) == 0) { red[wid * 2] = s; red[wid * 2 + 1] = sq; }
    __syncthreads();
    if (tid == 0) {
        parts[slice * 32 + part * 2]     = red[0] + red[2] + red[4] + red[6];
        parts[slice * 32 + part * 2 + 1] = red[1] + red[3] + red[5] + red[7];
    }
}

__global__ __launch_bounds__(256)
void apply_kernel(float* __restrict__ att, const float* __restrict__ parts)
{
    const int i4 = blockIdx.x * 256 + threadIdx.x;
    const size_t fl = (size_t)i4 * 4;
    const int slice = (int)(fl >> 17);
    float S = 0.f, SQ = 0.f;
    #pragma unroll
    for (int p = 0; p < 16; ++p) {      // uniform -> scalarized loads
        S  += parts[slice * 32 + p * 2];
        SQ += parts[slice * 32 + p * 2 + 1];
    }
    const float N = (float)(L_SEQ * E_DIM);
    float mean = S / N;
    float var  = SQ / N - mean * mean;
    float inv  = rsqrtf(var + EPSV);
    float4 v = *reinterpret_cast<const float4*>(att + fl);
    float4 o;
    o.x = (v.x - mean) * inv;
    o.y = (v.y - mean) * inv;
    o.z = (v.z - mean) * inv;
    o.w = (v.w - mean) * inv;
    *reinterpret_cast<float4*>(att + fl) = o;   // in place
}

// ---------------------------------------------------------------------------
extern "C" void kernel_launch(void* const* d_in, const int* in_sizes, int n_in,
                              void* d_out, int out_size, void* d_ws, size_t ws_size,
                              hipStream_t stream)
{
    const float* info = (const float*)d_in[0];
    const float* Wq   = (const float*)d_in[1];
    const float* bq   = (const float*)d_in[2];
    const float* Wk   = (const float*)d_in[3];
    const float* bk   = (const float*)d_in[4];
    const float* Wv   = (const float*)d_in[5];
    const float* bv   = (const float*)d_in[6];

    // Workspace: 13 MB total (att lives in d_out; stats via partials)
    char* ws = (char*)d_ws;
    f16*   Wt    = (f16*)(ws);                       //   0.00 MB, 294912 B
    float* bias  = (float*)(ws + 294912);            //   768 B
    float* parts = (float*)(ws + 295936);            //   2048 B
    f16*   q16   = (f16*)(ws + 1048576);             //   1 MB + 4 MB
    f16*   k16   = (f16*)(ws + 5242880);             //   5 MB + 4 MB
    f16*   v16   = (f16*)(ws + 9437184);             //   9 MB + 4 MB (end 13 MB)
    float* att   = (float*)d_out;

    prep_kernel<<<193, 256, 0, stream>>>(Wq, bq, Wk, bk, Wv, bv, Wt, bias);
    proj_mfma<<<256, 256, 0, stream>>>(info, Wt, bias, q16, k16, v16);
    attn_mfma<<<dim3(L_SEQ / 64, NSLICE), 256, 0, stream>>>(q16, k16, v16, att);
    stats_kernel<<<256, 256, 0, stream>>>(att, parts);
    apply_kernel<<<2048, 256, 0, stream>>>(att, parts);
}